// Round 2
// baseline (435.954 us; speedup 1.0000x reference)
//
#include <hip/hip_runtime.h>
#include <hip/hip_cooperative_groups.h>

namespace cg = cooperative_groups;

namespace {

constexpr int NXc = 200, NYc = 200;
constexpr int NCELL = NXc * NYc;
constexpr int TSTEPS = 300;          // scan length
constexpr int SRC_I = 30, SRC_J = 100;
constexpr int PNc = 20;              // PML_N
constexpr float Hc = 1.005f;         // DT*2.01

// ---- temporal blocking config ----
constexpr int T_SUB = 24;            // substeps per round (halo width)
constexpr int LT    = 64;            // loaded tile edge
constexpr int VT    = LT - 2 * T_SUB;          // 16 valid
constexpr int TI    = (NXc + VT - 1) / VT;     // 13
constexpr int TJ    = (NYc + VT - 1) / VT;     // 13
constexpr int NSTEP_TOT = TSTEPS - 1;          // 299 updates
constexpr int NROUND    = (NSTEP_TOT + T_SUB - 1) / T_SUB; // 13
constexpr int GSTRIDE = 304;

// ---- probe owner constants ----
constexpr int PROBE_I = 170;
constexpr int PTX = PROBE_I / VT;
constexpr int PRr = PROBE_I - (PTX * VT - T_SUB);
static_assert(PRr >= T_SUB && PRr < T_SUB + VT, "");
constexpr int PW  = PRr >> 4;
constexpr int PCc = PRr & 15;

constexpr int PJ0 = 50, PJ1 = 100, PJ2 = 150;
constexpr int PTY0 = PJ0 / VT; constexpr int PCOL0 = PJ0 - (PTY0 * VT - T_SUB);
constexpr int PTY1 = PJ1 / VT; constexpr int PCOL1 = PJ1 - (PTY1 * VT - T_SUB);
constexpr int PTY2 = PJ2 / VT; constexpr int PCOL2 = PJ2 - (PTY2 * VT - T_SUB);
static_assert(PCOL0 >= T_SUB && PCOL0 < T_SUB + VT, "");
static_assert(PCOL1 >= T_SUB && PCOL1 < T_SUB + VT, "");
static_assert(PCOL2 >= T_SUB && PCOL2 < T_SUB + VT, "");
constexpr int PTID0 = (PW << 6) | PCOL0;
constexpr int PTID1 = (PW << 6) | PCOL1;
constexpr int PTID2 = (PW << 6) | PCOL2;

} // namespace

// DPP whole-wave shifts (GFX9 lineage, kept on CDNA4).
// wf_shl1 (0x130): data shifts toward lower lanes -> lane i gets lane i+1.
// wf_shr1 (0x138): lane i gets lane i-1. bound_ctrl=1 -> 0 for edge lanes.
// NOTE: stencil consumes ev+wv symmetrically, so the direction convention
// cannot affect the result; edge-lane zeros land only in invalid halo.
__device__ __forceinline__ float dpp_east(float v) {
    return __int_as_float(__builtin_amdgcn_update_dpp(
        0, __float_as_int(v), 0x130, 0xf, 0xf, true));
}
__device__ __forceinline__ float dpp_west(float v) {
    return __int_as_float(__builtin_amdgcn_update_dpp(
        0, __float_as_int(v), 0x138, 0xf, 0xf, true));
}

// ---------------------------------------------------------------------------
// One persistent cooperative kernel:
//  - per-tile P,Q,R coefficients computed once into registers (held 299 steps)
//  - 13 temporal-blocked rounds of <=24 substeps, grid.sync() between rounds,
//    y1/y2 valid interiors ping-pong through global (L2-resident)
//  - E/W neighbors via DPP (VALU), N/S run boundaries via double-buffered LDS
//    rows with ONE barrier per substep
//  - impulse response g[3][300] recorded by 3 probe threads; blocks 0..7 then
//    do the x-convolution + intensity + normalize (LTI in the source)
// ---------------------------------------------------------------------------
__global__ __launch_bounds__(256) void wave_coop(
    const float* __restrict__ x, const float* __restrict__ rho,
    float* __restrict__ out,
    float* __restrict__ a1, float* __restrict__ a2,
    float* __restrict__ b1, float* __restrict__ b2,
    float* __restrict__ g)
{
    cg::grid_group gridg = cg::this_grid();
    const int bid  = blockIdx.x;          // 0..168
    const int tx   = bid / TJ;            // tile row
    const int ty   = bid % TJ;            // tile col
    const int tid  = threadIdx.x;
    const int lane = tid & 63;            // local col
    const int w    = tid >> 6;            // wave: rows 16w..16w+15

    const int i0 = tx * VT - T_SUB;
    const int j0 = ty * VT - T_SUB;
    const int gj = j0 + lane;
    const bool jin = (gj >= 0) && (gj < NYc);

    if (bid == 0 && tid < 3) g[tid * GSTRIDE] = 0.f;   // g[p][0] = 0

    // ---- coefficients (once, kept in registers for all 299 steps) ----
    //   y = P*y1 - Q*y2 + R*(n+s+e+w)
    //   P = A*(8 - 4*c2/H^2), Q = A*(4-b), R = A*c2/H^2, A = 1/(4+b)
    float Pr[16], Qr[16], Rr[16], y1r[16], y2r[16];
    #pragma unroll
    for (int c = 0; c < 16; ++c) {
        int gi = i0 + (w << 4) + c;
        bool in = jin && (gi >= 0) && (gi < NXc);
        float Pv = 0.f, Qv = 0.f, Rv = 0.f;
        if (in) {
            int idx = gi * NYc + gj;
            float r  = rho[idx];
            float rn = (gi > 0)       ? rho[idx - NYc] : 0.f;
            float rs = (gi < NXc - 1) ? rho[idx + NYc] : 0.f;
            float rw = (gj > 0)       ? rho[idx - 1]   : 0.f;
            float re = (gj < NYc - 1) ? rho[idx + 1]   : 0.f;
            float lp = 0.5f * r + 0.125f * (rn + rs + rw + re);

            float t_eta = tanhf(100.f * 0.5f);
            float denom = t_eta + tanhf(100.f * (1.f - 0.5f));
            float rho_p = (t_eta + tanhf(100.f * (lp - 0.5f))) / denom;
            float cc = 1.0f + (0.9f - 1.0f) * rho_p;
            float c2 = cc * cc;

            float ui = 0.f, uj = 0.f;
            if (gi <= PNc) ui = (float)(PNc - gi) * 0.05f;
            else if (gi >= NXc - PNc - 1) ui = (float)(gi - (NXc - PNc - 1)) * 0.05f;
            if (gj <= PNc) uj = (float)(PNc - gj) * 0.05f;
            else if (gj >= NYc - PNc - 1) uj = (float)(gj - (NYc - PNc - 1)) * 0.05f;
            float ui2 = ui * ui, uj2 = uj * uj;
            float bx = 3.0f * ui2 * ui2;
            float by = 3.0f * uj2 * uj2;
            float b  = sqrtf(bx * bx + by * by);

            float A = 1.0f / (4.0f + b);
            float h2inv = 1.0f / (Hc * Hc);
            Pv = A * (8.0f - 4.0f * c2 * h2inv);
            Qv = A * (4.0f - b);
            Rv = A * c2 * h2inv;
        }
        Pr[c] = Pv; Qr[c] = Qv; Rr[c] = Rv;
        // impulse initial condition y_0 = delta at source (consistent in halos)
        y1r[c] = (jin && (i0 + (w << 4) + c) == SRC_I && gj == SRC_J) ? 1.0f : 0.f;
        y2r[c] = 0.f;
    }

    const bool pb0 = (tx == PTX && ty == PTY0 && tid == PTID0);
    const bool pb1 = (tx == PTX && ty == PTY1 && tid == PTID1);
    const bool pb2 = (tx == PTX && ty == PTY2 && tid == PTID2);

    __shared__ float topSh[2][4][64];   // wave w's row 0, double-buffered
    __shared__ float botSh[2][4][64];   // wave w's row 15

    int s0 = 0;
    for (int l = 0; l < NROUND; ++l) {
        if (l > 0) {
            // reload full 64x64 y-tile (halo filled by neighbors' last round)
            const float* s1 = (l & 1) ? b1 : a1;
            const float* s2 = (l & 1) ? b2 : a2;
            #pragma unroll
            for (int c = 0; c < 16; ++c) {
                int gi = i0 + (w << 4) + c;
                bool in = jin && (gi >= 0) && (gi < NXc);
                int gidx = gi * NYc + gj;
                y1r[c] = in ? s1[gidx] : 0.f;
                y2r[c] = in ? s2[gidx] : 0.f;
            }
        }

        int ns = NSTEP_TOT - s0; if (ns > T_SUB) ns = T_SUB;
        for (int k = 0; k < ns; ++k) {
            int p = k & 1;
            topSh[p][w][lane] = y1r[0];
            botSh[p][w][lane] = y1r[15];
            __syncthreads();
            float nTop = (w > 0) ? botSh[p][w - 1][lane] : 0.f;
            float sBot = (w < 3) ? topSh[p][w + 1][lane] : 0.f;
            // no second barrier: next substep writes the other buffer, and a
            // wave can only reach that write after ALL waves passed this
            // barrier (reads of buf p precede the next barrier in program order)

            float yn[16];
            #pragma unroll
            for (int c = 0; c < 16; ++c) {
                float nv = (c == 0)  ? nTop : y1r[c - 1];
                float sv = (c == 15) ? sBot : y1r[c + 1];
                float ev = dpp_east(y1r[c]);
                float wv = dpp_west(y1r[c]);
                yn[c] = Pr[c] * y1r[c] - Qr[c] * y2r[c] + Rr[c] * ((nv + sv) + (ev + wv));
            }
            #pragma unroll
            for (int c = 0; c < 16; ++c) { y2r[c] = y1r[c]; y1r[c] = yn[c]; }

            int t = s0 + k + 1;
            if (pb0) g[0 * GSTRIDE + t] = y1r[PCc];
            if (pb1) g[1 * GSTRIDE + t] = y1r[PCc];
            if (pb2) g[2 * GSTRIDE + t] = y1r[PCc];
        }
        s0 += ns;

        if (l < NROUND - 1) {
            // write back valid interior
            float* d1 = (l & 1) ? a1 : b1;
            float* d2 = (l & 1) ? a2 : b2;
            #pragma unroll
            for (int c = 0; c < 16; ++c) {
                int r = (w << 4) + c;
                int gi = i0 + r;
                if (r >= T_SUB && r < T_SUB + VT &&
                    lane >= T_SUB && lane < T_SUB + VT &&
                    gi >= 0 && gi < NXc && gj >= 0 && gj < NYc) {
                    int gidx = gi * NYc + gj;
                    d1[gidx] = y1r[c];
                    d2[gidx] = y2r[c];
                }
            }
        }
        gridg.sync();
    }

    // ---- convolution + intensity + normalize (blocks 0..7, one per batch) ----
    if (bid < 8) {
        __shared__ float xs[304];
        __shared__ float gsm[3][304];
        __shared__ float red[3][4];

        for (int idx = tid; idx < TSTEPS; idx += 256) {
            xs[idx]     = x[bid * TSTEPS + idx];
            gsm[0][idx] = g[0 * GSTRIDE + idx];
            gsm[1][idx] = g[1 * GSTRIDE + idx];
            gsm[2][idx] = g[2 * GSTRIDE + idx];
        }
        __syncthreads();

        float acc0 = 0.f, acc1 = 0.f, acc2 = 0.f;
        for (int t = tid; t < TSTEPS; t += 256) {
            float c0 = 0.f, c1 = 0.f, c2 = 0.f;
            for (int s = 0; s <= t; ++s) {
                float xv = xs[s];
                c0 += xv * gsm[0][t - s];
                c1 += xv * gsm[1][t - s];
                c2 += xv * gsm[2][t - s];
            }
            acc0 += c0 * c0; acc1 += c1 * c1; acc2 += c2 * c2;
        }

        float accs[3] = {acc0, acc1, acc2};
        #pragma unroll
        for (int p = 0; p < 3; ++p) {
            float v = accs[p];
            #pragma unroll
            for (int off = 32; off > 0; off >>= 1) v += __shfl_down(v, off, 64);
            if ((tid & 63) == 0) red[p][tid >> 6] = v;
        }
        __syncthreads();
        if (tid == 0) {
            float I0 = red[0][0] + red[0][1] + red[0][2] + red[0][3];
            float I1 = red[1][0] + red[1][1] + red[1][2] + red[1][3];
            float I2 = red[2][0] + red[2][1] + red[2][2] + red[2][3];
            float inv = 1.0f / (I0 + I1 + I2);
            out[bid * 3 + 0] = I0 * inv;
            out[bid * 3 + 1] = I1 * inv;
            out[bid * 3 + 2] = I2 * inv;
        }
    }
}

// ---------------------------------------------------------------------------
extern "C" void kernel_launch(void* const* d_in, const int* in_sizes, int n_in,
                              void* d_out, int out_size, void* d_ws, size_t ws_size,
                              hipStream_t stream)
{
    const float* x   = (const float*)d_in[0];   // (8, 300)
    const float* rho = (const float*)d_in[1];   // (200, 200)
    float* out = (float*)d_out;                 // (8, 3) float32

    float* base = (float*)d_ws;
    float* a1 = base;
    float* a2 = a1 + NCELL;
    float* b1 = a2 + NCELL;
    float* b2 = b1 + NCELL;
    float* g  = b2 + NCELL;    // 3 * GSTRIDE floats

    void* args[] = { (void*)&x, (void*)&rho, (void*)&out,
                     (void*)&a1, (void*)&a2, (void*)&b1, (void*)&b2, (void*)&g };
    hipLaunchCooperativeKernel((const void*)wave_coop, dim3(TI * TJ), dim3(256),
                               args, 0, stream);
}

// Round 3
// 288.217 us; speedup vs baseline: 1.5126x; 1.5126x over previous
//
#include <hip/hip_runtime.h>

namespace {

constexpr int NXc = 200, NYc = 200;
constexpr int NCELL = NXc * NYc;
constexpr int TSTEPS = 300;
constexpr int SRC_I = 30, SRC_J = 100;
constexpr int PNc = 20;
constexpr float Hc = 1.005f;         // DT*2.01

// ---- temporal blocking config ----
constexpr int T_SUB = 24;            // substeps per round (halo width)
constexpr int LT    = 64;
constexpr int VT    = LT - 2 * T_SUB;          // 16
constexpr int TI    = (NXc + VT - 1) / VT;     // 13
constexpr int TJ    = (NYc + VT - 1) / VT;     // 13
constexpr int NB    = TI * TJ;                 // 169 blocks
constexpr int NSTEP_TOT = TSTEPS - 1;          // 299
constexpr int NROUND    = (NSTEP_TOT + T_SUB - 1) / T_SUB; // 13
constexpr int GSTRIDE = 304;

// barrier slots: bar[0..15] counters, bar[16..31] flags (one per round)
constexpr int BAR_WORDS = 32;

// ---- probe owner constants ----
constexpr int PROBE_I = 170;
constexpr int PTX = PROBE_I / VT;
constexpr int PRr = PROBE_I - (PTX * VT - T_SUB);
static_assert(PRr >= T_SUB && PRr < T_SUB + VT, "");
constexpr int PW  = PRr >> 4;
constexpr int PCc = PRr & 15;

constexpr int PJ0 = 50, PJ1 = 100, PJ2 = 150;
constexpr int PTY0 = PJ0 / VT; constexpr int PCOL0 = PJ0 - (PTY0 * VT - T_SUB);
constexpr int PTY1 = PJ1 / VT; constexpr int PCOL1 = PJ1 - (PTY1 * VT - T_SUB);
constexpr int PTY2 = PJ2 / VT; constexpr int PCOL2 = PJ2 - (PTY2 * VT - T_SUB);
static_assert(PCOL0 >= T_SUB && PCOL0 < T_SUB + VT, "");
static_assert(PCOL1 >= T_SUB && PCOL1 < T_SUB + VT, "");
static_assert(PCOL2 >= T_SUB && PCOL2 < T_SUB + VT, "");
constexpr int PTID0 = (PW << 6) | PCOL0;
constexpr int PTID1 = (PW << 6) | PCOL1;
constexpr int PTID2 = (PW << 6) | PCOL2;

// probe L1 distances from source (g[p][t] == 0 exactly for t < PD[p])
constexpr int PD0 = 190, PD1 = 140, PD2 = 190;

} // namespace

// DPP whole-wave shifts; stencil consumes ev+wv symmetrically so the
// direction convention cannot change the sum; bound_ctrl zeros land in halo.
__device__ __forceinline__ float dpp_east(float v) {
    return __int_as_float(__builtin_amdgcn_update_dpp(
        0, __float_as_int(v), 0x130, 0xf, 0xf, true));
}
__device__ __forceinline__ float dpp_west(float v) {
    return __int_as_float(__builtin_amdgcn_update_dpp(
        0, __float_as_int(v), 0x138, 0xf, 0xf, true));
}

// one-shot grid barrier, slot r. Per-round counter+flag, zeroed by bar_init
// each replay. Release: __threadfence (agent wbl2) before arrival atomic.
// Acquire: relaxed spin + __threadfence (agent inv) after.
__device__ __forceinline__ void grid_bar(unsigned* bar, int r, int tid) {
    __syncthreads();
    if (tid == 0) {
        __threadfence();
        unsigned a = atomicAdd(&bar[r], 1u);
        if (a == (unsigned)(NB - 1)) {
            __threadfence();
            __hip_atomic_store(&bar[16 + r], 1u, __ATOMIC_RELAXED,
                               __HIP_MEMORY_SCOPE_AGENT);
        } else {
            while (__hip_atomic_load(&bar[16 + r], __ATOMIC_RELAXED,
                                     __HIP_MEMORY_SCOPE_AGENT) == 0u)
                __builtin_amdgcn_s_sleep(1);
        }
        __threadfence();
    }
    __syncthreads();
}

__global__ __launch_bounds__(64) void bar_init(unsigned* bar) {
    if (threadIdx.x < BAR_WORDS) bar[threadIdx.x] = 0u;
}

// ---------------------------------------------------------------------------
__global__ __launch_bounds__(256) void wave_coop(
    const float* __restrict__ x, const float* __restrict__ rho,
    float* __restrict__ out,
    float* __restrict__ a1, float* __restrict__ a2,
    float* __restrict__ b1, float* __restrict__ b2,
    float* __restrict__ g, unsigned* __restrict__ bar)
{
    const int bid  = blockIdx.x;          // 0..168
    const int tx   = bid / TJ;
    const int ty   = bid % TJ;
    const int tid  = threadIdx.x;
    const int lane = tid & 63;
    const int w    = tid >> 6;

    const int i0 = tx * VT - T_SUB;
    const int j0 = ty * VT - T_SUB;
    const int gj = j0 + lane;
    const bool jin = (gj >= 0) && (gj < NYc);

    if (bid == 0 && tid < 3) g[tid * GSTRIDE] = 0.f;   // g[p][0] = 0

    // light-cone distance of the (unclipped) loaded region from the source
    int di = i0 - SRC_I; if (di < 0) di = SRC_I - (i0 + LT - 1); if (di < 0) di = 0;
    int dj = j0 - SRC_J; if (dj < 0) dj = SRC_J - (j0 + LT - 1); if (dj < 0) dj = 0;
    const int Dtile = di + dj;

    // ---- coefficients (once, register-resident for all 299 steps) ----
    float Pr[16], Qr[16], Rr[16], y1r[16], y2r[16];
    #pragma unroll
    for (int c = 0; c < 16; ++c) {
        int gi = i0 + (w << 4) + c;
        bool in = jin && (gi >= 0) && (gi < NXc);
        float Pv = 0.f, Qv = 0.f, Rv = 0.f;
        if (in) {
            int idx = gi * NYc + gj;
            float r  = rho[idx];
            float rn = (gi > 0)       ? rho[idx - NYc] : 0.f;
            float rs = (gi < NXc - 1) ? rho[idx + NYc] : 0.f;
            float rw = (gj > 0)       ? rho[idx - 1]   : 0.f;
            float re = (gj < NYc - 1) ? rho[idx + 1]   : 0.f;
            float lp = 0.5f * r + 0.125f * (rn + rs + rw + re);

            float t_eta = tanhf(100.f * 0.5f);
            float denom = t_eta + tanhf(100.f * (1.f - 0.5f));
            float rho_p = (t_eta + tanhf(100.f * (lp - 0.5f))) / denom;
            float cc = 1.0f + (0.9f - 1.0f) * rho_p;
            float c2 = cc * cc;

            float ui = 0.f, uj = 0.f;
            if (gi <= PNc) ui = (float)(PNc - gi) * 0.05f;
            else if (gi >= NXc - PNc - 1) ui = (float)(gi - (NXc - PNc - 1)) * 0.05f;
            if (gj <= PNc) uj = (float)(PNc - gj) * 0.05f;
            else if (gj >= NYc - PNc - 1) uj = (float)(gj - (NYc - PNc - 1)) * 0.05f;
            float ui2 = ui * ui, uj2 = uj * uj;
            float bx = 3.0f * ui2 * ui2;
            float by = 3.0f * uj2 * uj2;
            float b  = sqrtf(bx * bx + by * by);

            float A = 1.0f / (4.0f + b);
            float h2inv = 1.0f / (Hc * Hc);
            Pv = A * (8.0f - 4.0f * c2 * h2inv);
            Qv = A * (4.0f - b);
            Rv = A * c2 * h2inv;
        }
        Pr[c] = Pv; Qr[c] = Qv; Rr[c] = Rv;
        y1r[c] = (jin && (i0 + (w << 4) + c) == SRC_I && gj == SRC_J) ? 1.0f : 0.f;
        y2r[c] = 0.f;
    }

    const bool pb0 = (tx == PTX && ty == PTY0 && tid == PTID0);
    const bool pb1 = (tx == PTX && ty == PTY1 && tid == PTID1);
    const bool pb2 = (tx == PTX && ty == PTY2 && tid == PTID2);

    __shared__ float topSh[2][4][64];
    __shared__ float botSh[2][4][64];

    int s0 = 0;
    for (int l = 0; l < NROUND; ++l) {
        int ns = NSTEP_TOT - s0; if (ns > T_SUB) ns = T_SUB;
        const bool active = (Dtile <= s0 + ns);   // field nonzero on tile this round?

        if (active) {
            if (l > 0) {
                const float* s1 = (l & 1) ? b1 : a1;
                const float* s2 = (l & 1) ? b2 : a2;
                #pragma unroll
                for (int c = 0; c < 16; ++c) {
                    int gi = i0 + (w << 4) + c;
                    bool in = jin && (gi >= 0) && (gi < NXc);
                    int gidx = gi * NYc + gj;
                    y1r[c] = in ? s1[gidx] : 0.f;
                    y2r[c] = in ? s2[gidx] : 0.f;
                }
            }

            for (int k = 0; k < ns; ++k) {
                int p = k & 1;
                topSh[p][w][lane] = y1r[0];
                botSh[p][w][lane] = y1r[15];
                __syncthreads();
                float nTop = (w > 0) ? botSh[p][w - 1][lane] : 0.f;
                float sBot = (w < 3) ? topSh[p][w + 1][lane] : 0.f;
                // single barrier: next substep writes the other buffer and is
                // unreachable until all waves pass this barrier

                float yn[16];
                #pragma unroll
                for (int c = 0; c < 16; ++c) {
                    float nv = (c == 0)  ? nTop : y1r[c - 1];
                    float sv = (c == 15) ? sBot : y1r[c + 1];
                    float ev = dpp_east(y1r[c]);
                    float wv = dpp_west(y1r[c]);
                    yn[c] = Pr[c] * y1r[c] - Qr[c] * y2r[c] + Rr[c] * ((nv + sv) + (ev + wv));
                }
                #pragma unroll
                for (int c = 0; c < 16; ++c) { y2r[c] = y1r[c]; y1r[c] = yn[c]; }

                int t = s0 + k + 1;
                if (pb0) g[0 * GSTRIDE + t] = y1r[PCc];
                if (pb1) g[1 * GSTRIDE + t] = y1r[PCc];
                if (pb2) g[2 * GSTRIDE + t] = y1r[PCc];
            }
        } else {
            // field identically zero on this tile all round: registers stay 0;
            // probe owners still record zeros
            if (pb0) for (int k = 0; k < ns; ++k) g[0 * GSTRIDE + s0 + k + 1] = 0.f;
            if (pb1) for (int k = 0; k < ns; ++k) g[1 * GSTRIDE + s0 + k + 1] = 0.f;
            if (pb2) for (int k = 0; k < ns; ++k) g[2 * GSTRIDE + s0 + k + 1] = 0.f;
        }
        s0 += ns;

        if (l < NROUND - 1) {
            // write back valid interior (zeros if inactive — neighbors' future halo)
            float* d1 = (l & 1) ? a1 : b1;
            float* d2 = (l & 1) ? a2 : b2;
            #pragma unroll
            for (int c = 0; c < 16; ++c) {
                int r = (w << 4) + c;
                int gi = i0 + r;
                if (r >= T_SUB && r < T_SUB + VT &&
                    lane >= T_SUB && lane < T_SUB + VT &&
                    gi >= 0 && gi < NXc && gj >= 0 && gj < NYc) {
                    int gidx = gi * NYc + gj;
                    d1[gidx] = y1r[c];
                    d2[gidx] = y2r[c];
                }
            }
        }
        grid_bar(bar, l, tid);
    }

    // ---- convolution + intensity + normalize (blocks 0..7, one per batch) ----
    // g[p][t] == 0 exactly for t < PD[p] (light cone), so trim the inner sums.
    if (bid < 8) {
        __shared__ float xs[304];
        __shared__ float gsm[3][304];
        __shared__ float red[3][4];

        for (int idx = tid; idx < TSTEPS; idx += 256) {
            xs[idx]     = x[bid * TSTEPS + idx];
            gsm[0][idx] = g[0 * GSTRIDE + idx];
            gsm[1][idx] = g[1 * GSTRIDE + idx];
            gsm[2][idx] = g[2 * GSTRIDE + idx];
        }
        __syncthreads();

        float acc0 = 0.f, acc1 = 0.f, acc2 = 0.f;
        for (int t = tid; t < TSTEPS; t += 256) {
            float c0 = 0.f, c1 = 0.f, c2 = 0.f;
            int m1 = t - PD1;
            for (int s = 0; s <= m1; ++s) c1 += xs[s] * gsm[1][t - s];
            int m0 = t - PD0;   // PD0 == PD2
            for (int s = 0; s <= m0; ++s) {
                float xv = xs[s];
                c0 += xv * gsm[0][t - s];
                c2 += xv * gsm[2][t - s];
            }
            acc0 += c0 * c0; acc1 += c1 * c1; acc2 += c2 * c2;
        }

        float accs[3] = {acc0, acc1, acc2};
        #pragma unroll
        for (int p = 0; p < 3; ++p) {
            float v = accs[p];
            #pragma unroll
            for (int off = 32; off > 0; off >>= 1) v += __shfl_down(v, off, 64);
            if ((tid & 63) == 0) red[p][tid >> 6] = v;
        }
        __syncthreads();
        if (tid == 0) {
            float I0 = red[0][0] + red[0][1] + red[0][2] + red[0][3];
            float I1 = red[1][0] + red[1][1] + red[1][2] + red[1][3];
            float I2 = red[2][0] + red[2][1] + red[2][2] + red[2][3];
            float inv = 1.0f / (I0 + I1 + I2);
            out[bid * 3 + 0] = I0 * inv;
            out[bid * 3 + 1] = I1 * inv;
            out[bid * 3 + 2] = I2 * inv;
        }
    }
}

// ---------------------------------------------------------------------------
extern "C" void kernel_launch(void* const* d_in, const int* in_sizes, int n_in,
                              void* d_out, int out_size, void* d_ws, size_t ws_size,
                              hipStream_t stream)
{
    const float* x   = (const float*)d_in[0];   // (8, 300)
    const float* rho = (const float*)d_in[1];   // (200, 200)
    float* out = (float*)d_out;                 // (8, 3) float32

    float* base = (float*)d_ws;
    float* a1 = base;
    float* a2 = a1 + NCELL;
    float* b1 = a2 + NCELL;
    float* b2 = b1 + NCELL;
    float* g  = b2 + NCELL;                     // 3 * GSTRIDE
    unsigned* bar = (unsigned*)(g + 3 * GSTRIDE);

    bar_init<<<1, 64, 0, stream>>>(bar);

    void* args[] = { (void*)&x, (void*)&rho, (void*)&out,
                     (void*)&a1, (void*)&a2, (void*)&b1, (void*)&b2,
                     (void*)&g, (void*)&bar };
    hipLaunchCooperativeKernel((const void*)wave_coop, dim3(NB), dim3(256),
                               args, 0, stream);
}